// Round 10
// baseline (253.629 us; speedup 1.0000x reference)
//
#include <hip/hip_runtime.h>
#include <hip/hip_bf16.h>
#include <stdint.h>

// Problem constants
// x: [8,32,32,32] f32; G=16 -> pooled [8,32,16,16]; Pg=15, P=225; D=130; 2D=260
// HIDDEN=256, NOUT=128. leaky_relu slope 0.01.
#define NB 8
#define NP 225      // patches per image
#define PGRID 15    // 15x15 patch grid
#define DH 256      // hidden
#define DIN 130     // per-node feature dim

typedef short    s16x8 __attribute__((ext_vector_type(8)));   // 8 bf16 frag (4 VGPRs)
typedef float    f32x4 __attribute__((ext_vector_type(4)));
typedef uint32_t u32x4 __attribute__((ext_vector_type(4)));

static __device__ __forceinline__ uint16_t f2bf(float f) {
    union { float f; uint32_t u; } a; a.f = f;
    uint32_t u = a.u;
    return (uint16_t)((u + 0x7FFFu + ((u >> 16) & 1u)) >> 16);  // RNE
}
// Plain scalar casts: compiler fuses pairs into v_cvt_pk_bf16_f32 (m240).
static __device__ __forceinline__ uint32_t pack2(float a, float b) {
    union { __hip_bfloat16 h[2]; uint32_t u; } cv;
    cv.h[0] = __float2bfloat16(a);
    cv.h[1] = __float2bfloat16(b);
    return cv.u;
}
static __device__ __forceinline__ float lrelu(float x) { return fmaxf(x, 0.01f * x); }

// ---------------------------------------------------------------------------
// K1 (fused prep): blocks 0..359 = pool+patch+U/V projection (+ accg zeroing);
//                  blocks 360..391 = W1 repack to fragment-linear bf16.
__global__ void prep_kernel(const float* __restrict__ x, const float* __restrict__ W0,
                            const float* __restrict__ b0, const float* __restrict__ W1,
                            float* __restrict__ U, float* __restrict__ V,
                            uint16_t* __restrict__ W1F, float* __restrict__ accg) {
    int blk = blockIdx.x;
    if (blk >= 360) {
        // ---- W1 repack
        int t = (blk - 360) * 256 + threadIdx.x;   // 8192 threads = 128 slots * 64 lanes
        int slot = t >> 6, l = t & 63;
        int nf = slot >> 3, ks = slot & 7;
        int n = nf * 16 + (l & 15);
        int kb = l >> 4;
        uint32_t pk[4];
        #pragma unroll
        for (int e2 = 0; e2 < 4; ++e2) {
            int k = ks * 32 + kb * 8 + 2 * e2;
            uint32_t lo = f2bf(W1[k * DH + n]);
            uint32_t hi = f2bf(W1[(k + 1) * DH + n]);
            pk[e2] = lo | (hi << 16);
        }
        reinterpret_cast<uint4*>(W1F)[t] = make_uint4(pk[0], pk[1], pk[2], pk[3]);
        return;
    }
    // ---- U/V projection
    int bb = blk / 45;
    int p0 = (blk % 45) * 5;
    if (blk % 45 == 0) accg[bb * DH + threadIdx.x] = 0.0f;   // replaces memset
    __shared__ float fl[5][DIN];
    int t = threadIdx.x;
    for (int idx = t; idx < 5 * DIN; idx += 256) {
        int pp = idx / DIN, f = idx % DIN;
        int p = p0 + pp;
        int r = p / PGRID, c = p % PGRID;
        float val;
        if (f < 128) {
            int ch = f >> 2, q = f & 3, ki = q >> 1, kj = q & 1;
            int R = r + ki, C = c + kj;                 // pooled coords (0..15)
            const float* xp = x + (((size_t)bb * 32 + ch) * 32 + 2 * R) * 32 + 2 * C;
            val = 0.25f * (xp[0] + xp[1] + xp[32] + xp[33]);
        } else {
            val = (f == 128) ? (float)(c - 7) : (float)(r - 7);  // cx, cy
        }
        fl[pp][f] = val;
    }
    __syncthreads();
    int n = t;  // 0..255
    float u[5] = {0, 0, 0, 0, 0}, v[5] = {0, 0, 0, 0, 0};
    for (int k = 0; k < DIN; ++k) {
        float wa = W0[k * DH + n];
        float wb = W0[(DIN + k) * DH + n];
        #pragma unroll
        for (int pp = 0; pp < 5; ++pp) {
            float f = fl[pp][k];
            u[pp] = fmaf(f, wa, u[pp]);
            v[pp] = fmaf(f, wb, v[pp]);
        }
    }
    float bb0 = b0[n];
    #pragma unroll
    for (int pp = 0; pp < 5; ++pp) {
        size_t base = ((size_t)bb * NP + p0 + pp) * DH + n;
        U[base] = u[pp] + bb0;  // fold b0 into U
        V[base] = v[pp];
    }
}

// ---------------------------------------------------------------------------
// K2: main relational GEMM + reduce. Barrier-free register-A, mf-SPLIT.
// R8/R9 spilled ~328 B/thread (WRITE 118MB): live set bv128+acc64+temps ~240+
// exceeded the 256-reg cap once the scheduler interleaved mf iterations.
// Fix: process mf in two sequential halves; only acc[2][4]=32 regs live
// per half -> peak ~205 regs. Costs 2x U-LDS reads (trivial).
// Block = (batch, j-tile 16, chunk of <=5 i-tiles), 4 waves, independent
// after the single Upad-staging barrier. Wave w owns N-slice [w*64,(w+1)*64)
// with persistent bv (128 regs). A built in registers, MFMA consumes
// immediately; no loop barriers -> waves overlap VALU-build with MFMA.
__global__ __launch_bounds__(256, 2) void main_kernel(
        const float* __restrict__ U, const float* __restrict__ V,
        const uint16_t* __restrict__ W1F, const float* __restrict__ b1,
        float* __restrict__ accg) {
    __shared__ float Upad[16 * 260];  // 16.25 KB, stride 260: 2-way max on reads
    const int JT = 15, CHUNKS = 12, TILESPC = 5;  // 11*5+2 = 57 i-tiles
    int blk = blockIdx.x;
    int bb = blk / (JT * CHUNKS);
    int rem = blk % (JT * CHUNKS);
    int jt = rem / CHUNKS, ch = rem % CHUNKS;
    int j0 = jt * 16;
    int tile0 = ch * TILESPC;
    int nt = min(TILESPC, 57 - tile0);
    int t = threadIdx.x, l = t & 63, w = t >> 6;

    // ---- stage U tile once (coalesced global reads)
    {
        int jj = t >> 4, kk = (t & 15) * 16;
        int jc = j0 + jj; if (jc >= NP) jc = NP - 1;   // clamp; jmask kills later
        const float* src = U + ((size_t)bb * NP + jc) * DH + kk;
        #pragma unroll
        for (int e = 0; e < 4; ++e)
            *reinterpret_cast<float4*>(&Upad[jj * 260 + kk + 4 * e]) =
                *reinterpret_cast<const float4*>(src + 4 * e);
    }
    // ---- persistent B fragments (wave's N=64 slice): 32 frags = 128 regs
    s16x8 bv[4][8];
    const s16x8* Bp = reinterpret_cast<const s16x8*>(W1F);
    #pragma unroll
    for (int nf = 0; nf < 4; ++nf)
        #pragma unroll
        for (int ks = 0; ks < 8; ++ks)
            bv[nf][ks] = Bp[((w * 4 + nf) * 8 + ks) * 64 + l];
    float b1v[4];
    #pragma unroll
    for (int nf = 0; nf < 4; ++nf) b1v[nf] = b1[w * 64 + nf * 16 + (l & 15)];
    int rowg = l >> 4;
    float jmask[4];
    #pragma unroll
    for (int r = 0; r < 4; ++r) jmask[r] = (j0 + rowg * 4 + r) < NP ? 1.0f : 0.0f;
    float psum[4] = {0.f, 0.f, 0.f, 0.f};
    int kb = l >> 4;
    const float* Urow = &Upad[(l & 15) * 260 + kb * 8];
    const float* Vbb = V + (size_t)bb * NP * DH + kb * 8;
    __syncthreads();   // the only barrier

    for (int itl = 0; itl < nt; ++itl) {
        int i0 = (tile0 + itl) * 4;
        #pragma unroll
        for (int half = 0; half < 2; ++half) {       // mf pair {2*half, 2*half+1}
            f32x4 acc[2][4];
            #pragma unroll
            for (int m2 = 0; m2 < 2; ++m2)
                #pragma unroll
                for (int nf = 0; nf < 4; ++nf)
                    acc[m2][nf] = (f32x4){b1v[nf], b1v[nf], b1v[nf], b1v[nf]};

            #pragma unroll
            for (int ks = 0; ks < 8; ++ks) {
                float4 ua = *reinterpret_cast<const float4*>(Urow + ks * 32);
                float4 ub = *reinterpret_cast<const float4*>(Urow + ks * 32 + 4);
                #pragma unroll
                for (int m2 = 0; m2 < 2; ++m2) {
                    int ic = i0 + half * 2 + m2; if (ic >= NP) ic = NP - 1;
                    const float* vp = Vbb + (size_t)ic * DH + ks * 32;
                    float4 va = *reinterpret_cast<const float4*>(vp);
                    float4 vb = *reinterpret_cast<const float4*>(vp + 4);
                    u32x4 aw;
                    aw.x = pack2(lrelu(ua.x + va.x), lrelu(ua.y + va.y));
                    aw.y = pack2(lrelu(ua.z + va.z), lrelu(ua.w + va.w));
                    aw.z = pack2(lrelu(ub.x + vb.x), lrelu(ub.y + vb.y));
                    aw.w = pack2(lrelu(ub.z + vb.z), lrelu(ub.w + vb.w));
                    s16x8 af = __builtin_bit_cast(s16x8, aw);
                    #pragma unroll
                    for (int nf = 0; nf < 4; ++nf)
                        acc[m2][nf] = __builtin_amdgcn_mfma_f32_16x16x32_bf16(
                            af, bv[nf][ks], acc[m2][nf], 0, 0, 0);
                }
            }

            // ---- epilogue for this half: lrelu + fma-masked row-sum
            #pragma unroll
            for (int m2 = 0; m2 < 2; ++m2) {
                if (i0 + half * 2 + m2 < NP) {
                    #pragma unroll
                    for (int r = 0; r < 4; ++r) {
                        #pragma unroll
                        for (int nf = 0; nf < 4; ++nf) {
                            float a = acc[m2][nf][r];
                            float h = fmaxf(a, 0.01f * a);
                            psum[nf] = fmaf(h, jmask[r], psum[nf]);
                        }
                    }
                }
            }
        }
    }

    // ---- block-level reduce + one atomicAdd set
    #pragma unroll
    for (int nf = 0; nf < 4; ++nf) {
        psum[nf] += __shfl_xor(psum[nf], 16);
        psum[nf] += __shfl_xor(psum[nf], 32);
    }
    if (l < 16) {
        #pragma unroll
        for (int nf = 0; nf < 4; ++nf)
            atomicAdd(&accg[bb * DH + w * 64 + nf * 16 + l], psum[nf]);
    }
}

// ---------------------------------------------------------------------------
// K3: out[b,o] = (accg[b,:]/P^2) @ Wout + bout
__global__ void out_kernel(const float* __restrict__ accg, const float* __restrict__ Wout,
                           const float* __restrict__ bout, float* __restrict__ out) {
    int bb = blockIdx.x;
    int o = threadIdx.x;  // 0..127
    float s = 0.f;
    for (int n = 0; n < DH; ++n)
        s = fmaf(accg[bb * DH + n], Wout[n * 128 + o], s);
    out[bb * 128 + o] = s * (1.0f / 50625.0f) + bout[o];
}

// ---------------------------------------------------------------------------
extern "C" void kernel_launch(void* const* d_in, const int* in_sizes, int n_in,
                              void* d_out, int out_size, void* d_ws, size_t ws_size,
                              hipStream_t stream) {
    const float* x    = (const float*)d_in[0];
    const float* W0   = (const float*)d_in[1];
    const float* b0   = (const float*)d_in[2];
    const float* W1   = (const float*)d_in[3];
    const float* b1   = (const float*)d_in[4];
    const float* Wout = (const float*)d_in[5];
    const float* bout = (const float*)d_in[6];
    float* out = (float*)d_out;

    char* ws = (char*)d_ws;
    float*    U    = (float*)(ws);                            // 8*225*256*4 = 1,843,200 B
    float*    V    = (float*)(ws + 1843200);                  // 1,843,200 B
    uint16_t* W1F  = (uint16_t*)(ws + 2 * 1843200);           // 131,072 B
    float*    accg = (float*)(ws + 2 * 1843200 + 131072);     // 8*256*4 = 8,192 B

    prep_kernel<<<392, 256, 0, stream>>>(x, W0, b0, W1, U, V, W1F, accg);
    main_kernel<<<NB * 15 * 12, 256, 0, stream>>>(U, V, W1F, b1, accg);
    out_kernel<<<NB, 128, 0, stream>>>(accg, Wout, bout, out);
}

// Round 11
// 92.563 us; speedup vs baseline: 2.7401x; 2.7401x over previous
//
#include <hip/hip_runtime.h>
#include <hip/hip_bf16.h>
#include <stdint.h>

// Problem constants
#define NB 8
#define NP 225      // patches per image
#define PGRID 15    // 15x15 patch grid
#define DH 256      // hidden
#define DIN 130     // per-node feature dim

typedef _Float16 f16x8 __attribute__((ext_vector_type(8)));   // 8 f16 = 4 VGPRs
typedef float    f32x4 __attribute__((ext_vector_type(4)));

static __device__ __forceinline__ float lrelu(float x) { return fmaxf(x, 0.01f * x); }

// ---------------------------------------------------------------------------
// K1 (fused prep): blocks 0..359 = pool+patch+U/V projection (f32 math, f16
// store) + accg zeroing; blocks 360..391 = W1 repack to fragment-linear f16.
//   U[b,p,n] = feats[b,p,:] @ W0[0:130, n] + b0[n]   (f16)
//   V[b,p,n] = feats[b,p,:] @ W0[130:260, n]         (f16)
//   W1F[((nf*8+ks)*64+l)*8+e] = f16(W1[k,n]), n=nf*16+(l&15), k=ks*32+(l>>4)*8+e
__global__ void prep_kernel(const float* __restrict__ x, const float* __restrict__ W0,
                            const float* __restrict__ b0, const float* __restrict__ W1,
                            _Float16* __restrict__ U, _Float16* __restrict__ V,
                            _Float16* __restrict__ W1F, float* __restrict__ accg) {
    int blk = blockIdx.x;
    if (blk >= 360) {
        int t = (blk - 360) * 256 + threadIdx.x;   // 8192 threads = 128 slots * 64 lanes
        int slot = t >> 6, l = t & 63;
        int nf = slot >> 3, ks = slot & 7;
        int n = nf * 16 + (l & 15);
        int kb = l >> 4;
        f16x8 wv;
        #pragma unroll
        for (int e = 0; e < 8; ++e) {
            int k = ks * 32 + kb * 8 + e;
            wv[e] = (_Float16)W1[k * DH + n];
        }
        reinterpret_cast<f16x8*>(W1F)[t] = wv;
        return;
    }
    int bb = blk / 45;
    int p0 = (blk % 45) * 5;
    if (blk % 45 == 0) accg[bb * DH + threadIdx.x] = 0.0f;   // replaces memset
    __shared__ float fl[5][DIN];
    int t = threadIdx.x;
    for (int idx = t; idx < 5 * DIN; idx += 256) {
        int pp = idx / DIN, f = idx % DIN;
        int p = p0 + pp;
        int r = p / PGRID, c = p % PGRID;
        float val;
        if (f < 128) {
            int ch = f >> 2, q = f & 3, ki = q >> 1, kj = q & 1;
            int R = r + ki, C = c + kj;                 // pooled coords (0..15)
            const float* xp = x + (((size_t)bb * 32 + ch) * 32 + 2 * R) * 32 + 2 * C;
            val = 0.25f * (xp[0] + xp[1] + xp[32] + xp[33]);
        } else {
            val = (f == 128) ? (float)(c - 7) : (float)(r - 7);  // cx, cy
        }
        fl[pp][f] = val;
    }
    __syncthreads();
    int n = t;  // 0..255
    float u[5] = {0, 0, 0, 0, 0}, v[5] = {0, 0, 0, 0, 0};
    for (int k = 0; k < DIN; ++k) {
        float wa = W0[k * DH + n];
        float wb = W0[(DIN + k) * DH + n];
        #pragma unroll
        for (int pp = 0; pp < 5; ++pp) {
            float f = fl[pp][k];
            u[pp] = fmaf(f, wa, u[pp]);
            v[pp] = fmaf(f, wb, v[pp]);
        }
    }
    float bb0 = b0[n];
    #pragma unroll
    for (int pp = 0; pp < 5; ++pp) {
        size_t base = ((size_t)bb * NP + p0 + pp) * DH + n;
        U[base] = (_Float16)(u[pp] + bb0);  // fold b0 into U
        V[base] = (_Float16)v[pp];
    }
}

// ---------------------------------------------------------------------------
// K2: main relational GEMM + reduce — R5 structure (proven 78.5us), f16 data.
// Block = (batch, j-tile 16, chunk of <=7 i-tiles). 4 waves.
// Wave w: persistent bv = N=64 slice of W1F in 128 regs; builds A slots mf=w.
// LDS cuts vs R5 (the measured bottleneck: 84% of LDS-port floor):
//   U staged as f16 (1 b128 per slot, was 2), V read as f16 (1 b128, was 2),
//   build in packed-f16 vectors (v_pk_add/mul/max, ~12 VALU/slot vs 28).
// A in LDS f16 frag-linear; mfma_f32_16x16x32_f16 (same rate/layout as bf16;
// A/B use the same k-mapping so any slot permutation cancels).
__global__ __launch_bounds__(256, 2) void main_kernel(
        const _Float16* __restrict__ U, const _Float16* __restrict__ V,
        const _Float16* __restrict__ W1F, const float* __restrict__ b1,
        float* __restrict__ accg) {
    __shared__ f16x8 Af[2048];            // 32 KB: [mf(4)][ks(8)][lane(64)] x 16B
    __shared__ _Float16 Upad[16 * 264];   // 8.25 KB; stride 264h=132dw==4 mod 32
    const int JT = 15, CHUNKS = 9, TILESPC = 7;  // 9*7=63 >= 57 i-tiles
    int blk = blockIdx.x;
    int bb = blk / (JT * CHUNKS);
    int rem = blk % (JT * CHUNKS);
    int jt = rem / CHUNKS, ch = rem % CHUNKS;
    int j0 = jt * 16;
    int tile0 = ch * TILESPC;
    int nt = min(TILESPC, 57 - tile0);
    int t = threadIdx.x, l = t & 63, w = t >> 6;

    // ---- stage U tile once (f16, coalesced: 16 threads/row x 32B)
    {
        int jj = t >> 4, kk = (t & 15) * 16;   // kk in halfs
        int jc = j0 + jj; if (jc >= NP) jc = NP - 1;
        const f16x8* src = reinterpret_cast<const f16x8*>(U + ((size_t)bb * NP + jc) * DH + kk);
        *reinterpret_cast<f16x8*>(&Upad[jj * 264 + kk])     = src[0];
        *reinterpret_cast<f16x8*>(&Upad[jj * 264 + kk + 8]) = src[1];
    }
    // ---- persistent B fragments (wave's N=64 slice): 32 frags = 128 regs
    f16x8 bv[4][8];
    const f16x8* Bp = reinterpret_cast<const f16x8*>(W1F);
    #pragma unroll
    for (int nf = 0; nf < 4; ++nf)
        #pragma unroll
        for (int ks = 0; ks < 8; ++ks)
            bv[nf][ks] = Bp[((w * 4 + nf) * 8 + ks) * 64 + l];
    float b1v[4];
    #pragma unroll
    for (int nf = 0; nf < 4; ++nf) b1v[nf] = b1[w * 64 + nf * 16 + (l & 15)];
    float psum[4] = {0.f, 0.f, 0.f, 0.f};
    int kb = l >> 4;
    const _Float16* Urow = &Upad[(l & 15) * 264 + kb * 8];
    __syncthreads();

    for (int itl = 0; itl < nt; ++itl) {
        int i0 = (tile0 + itl) * 4;
        int ii = i0 + w;
        int ic = ii < NP ? ii : NP - 1;
        const f16x8* Vrow = reinterpret_cast<const f16x8*>(V + ((size_t)bb * NP + ic) * DH);
        if (itl) __syncthreads();   // prev iter's A reads done before overwrite

        // ---- build A: wave w builds mf=w, 8 ks slots (packed-f16 math)
        #pragma unroll
        for (int ks = 0; ks < 8; ++ks) {
            f16x8 uv = *reinterpret_cast<const f16x8*>(Urow + ks * 32);
            f16x8 vv = Vrow[ks * 4 + kb];
            f16x8 s  = uv + vv;
            f16x8 a  = __builtin_elementwise_max(s, s * (_Float16)0.01f);
            Af[(w * 8 + ks) * 64 + l] = a;
        }
        __syncthreads();

        // ---- MFMA: acc init = b1 (col = lane&15, same for all rows)
        f32x4 acc[4][4];
        #pragma unroll
        for (int mf = 0; mf < 4; ++mf)
            #pragma unroll
            for (int nf = 0; nf < 4; ++nf)
                acc[mf][nf] = (f32x4){b1v[nf], b1v[nf], b1v[nf], b1v[nf]};
        #pragma unroll
        for (int ks = 0; ks < 8; ++ks) {
            f16x8 av[4];
            #pragma unroll
            for (int mf = 0; mf < 4; ++mf) av[mf] = Af[(mf * 8 + ks) * 64 + l];
            #pragma unroll
            for (int mf = 0; mf < 4; ++mf)
                #pragma unroll
                for (int nf = 0; nf < 4; ++nf)
                    acc[mf][nf] = __builtin_amdgcn_mfma_f32_16x16x32_f16(
                        av[mf], bv[nf][ks], acc[mf][nf], 0, 0, 0);
        }

        // ---- epilogue: lrelu + masked row-sum into psum (held across iters)
        int rowg = l >> 4;  // C row = rowg*4 + r
        #pragma unroll
        for (int mf = 0; mf < 4; ++mf) {
            bool iv = (i0 + mf) < NP;
            #pragma unroll
            for (int r = 0; r < 4; ++r) {
                bool valid = iv && ((j0 + rowg * 4 + r) < NP);
                #pragma unroll
                for (int nf = 0; nf < 4; ++nf) {
                    float h = lrelu(acc[mf][nf][r]);
                    psum[nf] += valid ? h : 0.f;
                }
            }
        }
    }

    // ---- block-level reduce + one atomicAdd set
    #pragma unroll
    for (int nf = 0; nf < 4; ++nf) {
        psum[nf] += __shfl_xor(psum[nf], 16);
        psum[nf] += __shfl_xor(psum[nf], 32);
    }
    if (l < 16) {
        #pragma unroll
        for (int nf = 0; nf < 4; ++nf)
            atomicAdd(&accg[bb * DH + w * 64 + nf * 16 + l], psum[nf]);
    }
}

// ---------------------------------------------------------------------------
// K3: out[b,o] = (accg[b,:]/P^2) @ Wout + bout
__global__ void out_kernel(const float* __restrict__ accg, const float* __restrict__ Wout,
                           const float* __restrict__ bout, float* __restrict__ out) {
    int bb = blockIdx.x;
    int o = threadIdx.x;  // 0..127
    float s = 0.f;
    for (int n = 0; n < DH; ++n)
        s = fmaf(accg[bb * DH + n], Wout[n * 128 + o], s);
    out[bb * 128 + o] = s * (1.0f / 50625.0f) + bout[o];
}

// ---------------------------------------------------------------------------
extern "C" void kernel_launch(void* const* d_in, const int* in_sizes, int n_in,
                              void* d_out, int out_size, void* d_ws, size_t ws_size,
                              hipStream_t stream) {
    const float* x    = (const float*)d_in[0];
    const float* W0   = (const float*)d_in[1];
    const float* b0   = (const float*)d_in[2];
    const float* W1   = (const float*)d_in[3];
    const float* b1   = (const float*)d_in[4];
    const float* Wout = (const float*)d_in[5];
    const float* bout = (const float*)d_in[6];
    float* out = (float*)d_out;

    char* ws = (char*)d_ws;
    _Float16* U    = (_Float16*)(ws);                      // 8*225*256*2 =   921,600 B
    _Float16* V    = (_Float16*)(ws + 921600);             //                 921,600 B
    _Float16* W1F  = (_Float16*)(ws + 2 * 921600);         // 256*256*2  =   131,072 B
    float*    accg = (float*)(ws + 2 * 921600 + 131072);   // 8*256*4    =     8,192 B

    prep_kernel<<<392, 256, 0, stream>>>(x, W0, b0, W1, U, V, W1F, accg);
    main_kernel<<<NB * 15 * 9, 256, 0, stream>>>(U, V, W1F, b1, accg);
    out_kernel<<<NB, 128, 0, stream>>>(accg, Wout, bout, out);
}

// Round 12
// 86.023 us; speedup vs baseline: 2.9484x; 1.0760x over previous
//
#include <hip/hip_runtime.h>
#include <hip/hip_bf16.h>
#include <stdint.h>

// Problem constants
#define NB 8
#define NP 225      // patches per image
#define PGRID 15    // 15x15 patch grid
#define DH 256      // hidden
#define DIN 130     // per-node feature dim

typedef _Float16 f16x8 __attribute__((ext_vector_type(8)));   // 8 f16 = 4 VGPRs
typedef float    f32x4 __attribute__((ext_vector_type(4)));

static __device__ __forceinline__ float lrelu(float x) { return fmaxf(x, 0.01f * x); }

// ---------------------------------------------------------------------------
// K1 (fused prep): blocks 0..359 = pool+patch+U/V projection (f32 math, f16
// store) + accg zeroing; blocks 360..391 = W1 repack to fragment-linear f16.
__global__ void prep_kernel(const float* __restrict__ x, const float* __restrict__ W0,
                            const float* __restrict__ b0, const float* __restrict__ W1,
                            _Float16* __restrict__ U, _Float16* __restrict__ V,
                            _Float16* __restrict__ W1F, float* __restrict__ accg) {
    int blk = blockIdx.x;
    if (blk >= 360) {
        int t = (blk - 360) * 256 + threadIdx.x;   // 8192 threads = 128 slots * 64 lanes
        int slot = t >> 6, l = t & 63;
        int nf = slot >> 3, ks = slot & 7;
        int n = nf * 16 + (l & 15);
        int kb = l >> 4;
        f16x8 wv;
        #pragma unroll
        for (int e = 0; e < 8; ++e) {
            int k = ks * 32 + kb * 8 + e;
            wv[e] = (_Float16)W1[k * DH + n];
        }
        reinterpret_cast<f16x8*>(W1F)[t] = wv;
        return;
    }
    int bb = blk / 45;
    int p0 = (blk % 45) * 5;
    if (blk % 45 == 0) accg[bb * DH + threadIdx.x] = 0.0f;   // replaces memset
    __shared__ float fl[5][DIN];
    int t = threadIdx.x;
    for (int idx = t; idx < 5 * DIN; idx += 256) {
        int pp = idx / DIN, f = idx % DIN;
        int p = p0 + pp;
        int r = p / PGRID, c = p % PGRID;
        float val;
        if (f < 128) {
            int ch = f >> 2, q = f & 3, ki = q >> 1, kj = q & 1;
            int R = r + ki, C = c + kj;                 // pooled coords (0..15)
            const float* xp = x + (((size_t)bb * 32 + ch) * 32 + 2 * R) * 32 + 2 * C;
            val = 0.25f * (xp[0] + xp[1] + xp[32] + xp[33]);
        } else {
            val = (f == 128) ? (float)(c - 7) : (float)(r - 7);  // cx, cy
        }
        fl[pp][f] = val;
    }
    __syncthreads();
    int n = t;  // 0..255
    float u[5] = {0, 0, 0, 0, 0}, v[5] = {0, 0, 0, 0, 0};
    for (int k = 0; k < DIN; ++k) {
        float wa = W0[k * DH + n];
        float wb = W0[(DIN + k) * DH + n];
        #pragma unroll
        for (int pp = 0; pp < 5; ++pp) {
            float f = fl[pp][k];
            u[pp] = fmaf(f, wa, u[pp]);
            v[pp] = fmaf(f, wb, v[pp]);
        }
    }
    float bb0 = b0[n];
    #pragma unroll
    for (int pp = 0; pp < 5; ++pp) {
        size_t base = ((size_t)bb * NP + p0 + pp) * DH + n;
        U[base] = (_Float16)(u[pp] + bb0);  // fold b0 into U
        V[base] = (_Float16)v[pp];
    }
}

// ---------------------------------------------------------------------------
// K2: main relational GEMM + reduce — R11 structure + (a) asm-pinned resident
// B fragments, (b) chunk-V staged in LDS via global_load_lds.
// R11 evidence: VGPR_Count=128 == sizeof(bv) -> compiler was RELOADING B from
// L1/L2 inside the ks-loop (~200cyc each), serializing the MFMA phase. The
// "+v" pin forces bv to stay in VGPRs (peak ~225 < 256 cap of (256,2)).
// V rows for the whole chunk (28 x 512B, contiguous) are DMA'd to LDS once
// per block (14 x global_load_lds width-16, linear dest), removing per-iter
// V global latency. Build reads V from LDS (broadcast pattern).
__global__ __launch_bounds__(256, 2) void main_kernel(
        const _Float16* __restrict__ U, const _Float16* __restrict__ V,
        const _Float16* __restrict__ W1F, const float* __restrict__ b1,
        float* __restrict__ accg) {
    __shared__ f16x8 Af[2048];            // 32 KB: [mf(4)][ks(8)][lane(64)] x 16B
    __shared__ _Float16 Upad[16 * 264];   // 8.25 KB; stride 264h
    __shared__ _Float16 Vlds[28 * 256];   // 14 KB: chunk's V rows
    const int JT = 15, CHUNKS = 9, TILESPC = 7;  // 9*7=63 >= 57 i-tiles
    int blk = blockIdx.x;
    int bb = blk / (JT * CHUNKS);
    int rem = blk % (JT * CHUNKS);
    int jt = rem / CHUNKS, ch = rem % CHUNKS;
    int j0 = jt * 16;
    int tile0 = ch * TILESPC;
    int nt = min(TILESPC, 57 - tile0);
    int t = threadIdx.x, l = t & 63, w = t >> 6;

    // ---- DMA chunk V rows to LDS: 28 rows x 512B = 14 x 1KB instrs.
    // Rows are contiguous in V; tail chunks read past valid rows into ws
    // scratch (harmless; masked in epilogue).
    {
        const _Float16* Vsrc = V + ((size_t)bb * NP + tile0 * 4) * DH;
        for (int q = w * 4; q < 14 && q < w * 4 + 4; ++q) {
            __builtin_amdgcn_global_load_lds(
                (const __attribute__((address_space(1))) void*)(Vsrc + q * 512 + (size_t)l * 8),
                (__attribute__((address_space(3))) void*)(&Vlds[q * 512]),
                16, 0, 0);
        }
    }
    // ---- stage U tile once (f16, coalesced: 16 threads/row x 32B)
    {
        int jj = t >> 4, kk = (t & 15) * 16;   // kk in halfs
        int jc = j0 + jj; if (jc >= NP) jc = NP - 1;
        const f16x8* src = reinterpret_cast<const f16x8*>(U + ((size_t)bb * NP + jc) * DH + kk);
        *reinterpret_cast<f16x8*>(&Upad[jj * 264 + kk])     = src[0];
        *reinterpret_cast<f16x8*>(&Upad[jj * 264 + kk + 8]) = src[1];
    }
    // ---- B fragments (wave's N=64 slice): 32 frags = 128 regs, pinned below
    f16x8 bv[4][8];
    const f16x8* Bp = reinterpret_cast<const f16x8*>(W1F);
    #pragma unroll
    for (int nf = 0; nf < 4; ++nf)
        #pragma unroll
        for (int ks = 0; ks < 8; ++ks)
            bv[nf][ks] = Bp[((w * 4 + nf) * 8 + ks) * 64 + l];
    float b1v[4];
    #pragma unroll
    for (int nf = 0; nf < 4; ++nf) b1v[nf] = b1[w * 64 + nf * 16 + (l & 15)];
    float psum[4] = {0.f, 0.f, 0.f, 0.f};
    int kb = l >> 4;
    const _Float16* Urow = &Upad[(l & 15) * 264 + kb * 8];
    __syncthreads();   // drains vmcnt (Vlds DMA) + makes Upad visible

    for (int itl = 0; itl < nt; ++itl) {
        // pin bv: "+v" makes each frag non-rematerializable -> stays in VGPRs
        #pragma unroll
        for (int nf = 0; nf < 4; ++nf)
            #pragma unroll
            for (int ks = 0; ks < 8; ++ks)
                asm volatile("" : "+v"(bv[nf][ks]));

        int i0 = (tile0 + itl) * 4;
        int vrow = itl * 4 + w;     // wave w builds mf=w
        const f16x8* Vrow = reinterpret_cast<const f16x8*>(&Vlds[vrow * 256]);
        if (itl) __syncthreads();   // prev iter's A reads done before overwrite

        // ---- build A: wave w builds mf=w, 8 ks slots (packed-f16 math)
        #pragma unroll
        for (int ks = 0; ks < 8; ++ks) {
            f16x8 uv = *reinterpret_cast<const f16x8*>(Urow + ks * 32);
            f16x8 vv = Vrow[ks * 4 + kb];
            f16x8 s  = uv + vv;
            f16x8 a  = __builtin_elementwise_max(s, s * (_Float16)0.01f);
            Af[(w * 8 + ks) * 64 + l] = a;
        }
        __syncthreads();

        // ---- MFMA: acc init = b1 (col = lane&15, same for all rows)
        f32x4 acc[4][4];
        #pragma unroll
        for (int mf = 0; mf < 4; ++mf)
            #pragma unroll
            for (int nf = 0; nf < 4; ++nf)
                acc[mf][nf] = (f32x4){b1v[nf], b1v[nf], b1v[nf], b1v[nf]};
        #pragma unroll
        for (int ks = 0; ks < 8; ++ks) {
            f16x8 av[4];
            #pragma unroll
            for (int mf = 0; mf < 4; ++mf) av[mf] = Af[(mf * 8 + ks) * 64 + l];
            #pragma unroll
            for (int mf = 0; mf < 4; ++mf)
                #pragma unroll
                for (int nf = 0; nf < 4; ++nf)
                    acc[mf][nf] = __builtin_amdgcn_mfma_f32_16x16x32_f16(
                        av[mf], bv[nf][ks], acc[mf][nf], 0, 0, 0);
        }

        // ---- epilogue: lrelu + masked row-sum into psum (held across iters)
        int rowg = l >> 4;  // C row = rowg*4 + r
        #pragma unroll
        for (int mf = 0; mf < 4; ++mf) {
            bool iv = (i0 + mf) < NP;
            #pragma unroll
            for (int r = 0; r < 4; ++r) {
                bool valid = iv && ((j0 + rowg * 4 + r) < NP);
                #pragma unroll
                for (int nf = 0; nf < 4; ++nf) {
                    float h = lrelu(acc[mf][nf][r]);
                    psum[nf] += valid ? h : 0.f;
                }
            }
        }
    }

    // ---- block-level reduce + one atomicAdd set
    #pragma unroll
    for (int nf = 0; nf < 4; ++nf) {
        psum[nf] += __shfl_xor(psum[nf], 16);
        psum[nf] += __shfl_xor(psum[nf], 32);
    }
    if (l < 16) {
        #pragma unroll
        for (int nf = 0; nf < 4; ++nf)
            atomicAdd(&accg[bb * DH + w * 64 + nf * 16 + l], psum[nf]);
    }
}

// ---------------------------------------------------------------------------
// K3: out[b,o] = (accg[b,:]/P^2) @ Wout + bout
__global__ void out_kernel(const float* __restrict__ accg, const float* __restrict__ Wout,
                           const float* __restrict__ bout, float* __restrict__ out) {
    int bb = blockIdx.x;
    int o = threadIdx.x;  // 0..127
    float s = 0.f;
    for (int n = 0; n < DH; ++n)
        s = fmaf(accg[bb * DH + n], Wout[n * 128 + o], s);
    out[bb * 128 + o] = s * (1.0f / 50625.0f) + bout[o];
}

// ---------------------------------------------------------------------------
extern "C" void kernel_launch(void* const* d_in, const int* in_sizes, int n_in,
                              void* d_out, int out_size, void* d_ws, size_t ws_size,
                              hipStream_t stream) {
    const float* x    = (const float*)d_in[0];
    const float* W0   = (const float*)d_in[1];
    const float* b0   = (const float*)d_in[2];
    const float* W1   = (const float*)d_in[3];
    const float* b1   = (const float*)d_in[4];
    const float* Wout = (const float*)d_in[5];
    const float* bout = (const float*)d_in[6];
    float* out = (float*)d_out;

    char* ws = (char*)d_ws;
    _Float16* U    = (_Float16*)(ws);                      // 8*225*256*2 =   921,600 B
    _Float16* V    = (_Float16*)(ws + 921600);             //                 921,600 B
    _Float16* W1F  = (_Float16*)(ws + 2 * 921600);         // 256*256*2  =   131,072 B
    float*    accg = (float*)(ws + 2 * 921600 + 131072);   // 8*256*4    =     8,192 B

    prep_kernel<<<392, 256, 0, stream>>>(x, W0, b0, W1, U, V, W1F, accg);
    main_kernel<<<NB * 15 * 9, 256, 0, stream>>>(U, V, W1F, b1, accg);
    out_kernel<<<NB, 128, 0, stream>>>(accg, Wout, bout, out);
}